// Round 1
// baseline (2251.966 us; speedup 1.0000x reference)
//
#include <hip/hip_runtime.h>
#include <hip/hip_bf16.h>
#include <math.h>

#define SCALE 0.08838834764831845f  // 1/sqrt(128)

// ---------------- projection kernel ----------------
// grid (512, 12), block 256. Computes Q,K,V = x @ W into [h,b,t,e] layout.
__global__ __launch_bounds__(256)
void proj_kernel(const float* __restrict__ x,
                 const float* __restrict__ wq,
                 const float* __restrict__ wk,
                 const float* __restrict__ wv,
                 float* __restrict__ Q, float* __restrict__ K, float* __restrict__ V) {
    __shared__ float xst[128 * 16];   // transposed x tile: xst[kk][row]
    const int tid = threadIdx.x;
    const int rblk = blockIdx.x * 16;              // x-row base (0..8191)
    // load 16 rows x 128 cols, store transposed
    for (int ch = tid; ch < 512; ch += 256) {      // 512 float4 chunks
        const int r = ch >> 5;                     // 0..15
        const int c = (ch & 31) * 4;               // 0..124
        float4 v = reinterpret_cast<const float4*>(x + (size_t)rblk * 128)[ch];
        xst[(c + 0) * 16 + r] = v.x;
        xst[(c + 1) * 16 + r] = v.y;
        xst[(c + 2) * 16 + r] = v.z;
        xst[(c + 3) * 16 + r] = v.w;
    }
    __syncthreads();
    const int c = blockIdx.y * 256 + tid;          // 0..3071
    const int m = c >> 10;                         // 0 q, 1 k, 2 v
    const int cc = c & 1023;
    const float* W = (m == 0) ? wq : (m == 1) ? wk : wv;
    float* O = (m == 0) ? Q : (m == 1) ? K : V;
    float acc[16];
    #pragma unroll
    for (int i = 0; i < 16; ++i) acc[i] = 0.f;
    for (int kk = 0; kk < 128; ++kk) {
        const float w = W[kk * 1024 + cc];
        const float4* xv = reinterpret_cast<const float4*>(&xst[kk * 16]);
        float4 x0 = xv[0], x1 = xv[1], x2 = xv[2], x3 = xv[3];
        acc[0]  += x0.x * w; acc[1]  += x0.y * w; acc[2]  += x0.z * w; acc[3]  += x0.w * w;
        acc[4]  += x1.x * w; acc[5]  += x1.y * w; acc[6]  += x1.z * w; acc[7]  += x1.w * w;
        acc[8]  += x2.x * w; acc[9]  += x2.y * w; acc[10] += x2.z * w; acc[11] += x2.w * w;
        acc[12] += x3.x * w; acc[13] += x3.y * w; acc[14] += x3.z * w; acc[15] += x3.w * w;
    }
    const int h = cc >> 7, e = cc & 127;
    const int b = rblk >> 10, t = rblk & 1023;
    float* obase = O + (((size_t)(h * 8 + b) * 1024) + t) * 128 + e;
    #pragma unroll
    for (int i = 0; i < 16; ++i) obase[(size_t)i * 128] = acc[i];
}

// ---------------- gating (sel) kernel ----------------
// grid 8 (per batch), block 1024
__global__ __launch_bounds__(1024)
void sel_kernel(const float* __restrict__ x, const float* __restrict__ wsl,
                const float* __restrict__ bsl, float* __restrict__ sel) {
    __shared__ float part[8][128];
    __shared__ float xm[128];
    __shared__ float lg[8];
    const int b = blockIdx.x;
    const int tid = threadIdx.x;
    const int e = tid & 127, tc = tid >> 7;
    float s = 0.f;
    for (int t = 0; t < 128; ++t) {
        s += x[((size_t)b * 1024 + tc * 128 + t) * 128 + e];
    }
    part[tc][e] = s;
    __syncthreads();
    if (tid < 128) {
        float tot = 0.f;
        #pragma unroll
        for (int i = 0; i < 8; ++i) tot += part[i][tid];
        xm[tid] = tot * (1.0f / 1024.0f);
    }
    __syncthreads();
    if (tid < 8) {
        float d = 0.f;
        for (int e2 = 0; e2 < 128; ++e2) d += xm[e2] * wsl[tid * 128 + e2];
        lg[tid] = d + bsl[tid];
    }
    __syncthreads();
    if (tid == 0) {
        float mx = lg[0];
        for (int hh = 1; hh < 8; ++hh) mx = fmaxf(mx, lg[hh]);
        float se = 0.f; float ex[8];
        for (int hh = 0; hh < 8; ++hh) { ex[hh] = expf(lg[hh] - mx); se += ex[hh]; }
        for (int hh = 0; hh < 8; ++hh) sel[b * 8 + hh] = ex[hh] / se;
    }
}

// ---------------- fused attention kernel ----------------
// grid 4096 = 64 (h,b) * 64 q-tiles; block 512.
#define QT 16
#define SSTR 1026

__global__ __launch_bounds__(512)
void attn_kernel(const float* __restrict__ Q, const float* __restrict__ K,
                 const float* __restrict__ V, const int* __restrict__ mask,
                 const float* __restrict__ sel, float* __restrict__ out) {
    __shared__ float S[QT * SSTR];   // 65,664 B: fp32 score rows (padded stride)
    __shared__ float Qs[QT * 128];   //  8,192 B
    __shared__ float KT[128 * 65];   // 33,280 B: transposed K/V staging tile
    const int tid = threadIdx.x;
    const int hb = blockIdx.x >> 6;          // 0..63  (consecutive blocks share (h,b) -> L2 reuse)
    const int qt = blockIdx.x & 63;
    const int h = hb >> 3, b = hb & 7;
    const int t0 = qt * QT;
    const size_t hbbase = (size_t)(h * 8 + b) * 1024 * 128;

    // load Q tile, pre-scaled
    {
        float4 v = reinterpret_cast<const float4*>(Q + hbbase + (size_t)t0 * 128)[tid];
        v.x *= SCALE; v.y *= SCALE; v.z *= SCALE; v.w *= SCALE;
        reinterpret_cast<float4*>(Qs)[tid] = v;
    }

    const int tq = tid >> 5;          // 0..15
    const int tk = tid & 31;          // 0..31
    const int k0 = tk * 2;

    // ---- QK^T + mask ----
    for (int kt = 0; kt < 16; ++kt) {
        __syncthreads();  // protect KT (and Qs on first iter)
        for (int ch = tid; ch < 2048; ch += 512) {   // 64 rows x 128 cols as float4
            const int r = ch >> 5;
            const int c = (ch & 31) * 4;
            float4 v = reinterpret_cast<const float4*>(K + hbbase + (size_t)(kt * 64) * 128)[ch];
            KT[(c + 0) * 65 + r] = v.x;
            KT[(c + 1) * 65 + r] = v.y;
            KT[(c + 2) * 65 + r] = v.z;
            KT[(c + 3) * 65 + r] = v.w;
        }
        __syncthreads();
        float a0 = 0.f, a1 = 0.f;
        #pragma unroll 8
        for (int kk = 0; kk < 128; ++kk) {
            const float qv = Qs[tq * 128 + kk];
            a0 += qv * KT[kk * 65 + k0];
            a1 += qv * KT[kk * 65 + k0 + 1];
        }
        const int kg = kt * 64 + k0;
        const int* mrow = mask + ((size_t)b * 1024 + (t0 + tq)) * 1024 + kg;
        S[tq * SSTR + kg]     = mrow[0] ? -1e30f : a0;
        S[tq * SSTR + kg + 1] = mrow[1] ? -1e30f : a1;
    }
    __syncthreads();

    // ---- sparsemax per row (Michelot fixed-point, exact support) ----
    {
        const int r = tid >> 5;       // row 0..15
        const int g = tid & 31;       // 32 lanes per row
        float* Srow = &S[r * SSTR];
        float sum = 0.f; int cnt = 0;
        #pragma unroll 4
        for (int i = 0; i < 32; ++i) {
            const float z = Srow[g + 32 * i];
            if (z > -1e20f) { sum += z; cnt += 1; }   // exclude masked (-1e30)
        }
        #pragma unroll
        for (int mth = 1; mth < 32; mth <<= 1) {
            sum += __shfl_xor(sum, mth);
            cnt += __shfl_xor(cnt, mth);
        }
        float tau;
        if (cnt == 0) {
            tau = 3e38f;              // fully-masked row -> all-zero output
        } else {
            tau = (sum - 1.0f) / (float)cnt;
            int prev = cnt;
            for (int it = 0; it < 100; ++it) {
                float s2 = 0.f; int c2 = 0;
                #pragma unroll 4
                for (int i = 0; i < 32; ++i) {
                    const float z = Srow[g + 32 * i];
                    if (z > tau) { s2 += z; c2 += 1; }
                }
                #pragma unroll
                for (int mth = 1; mth < 32; mth <<= 1) {
                    s2 += __shfl_xor(s2, mth);
                    c2 += __shfl_xor(c2, mth);
                }
                if (c2 == prev) break;  // support stable -> tau is the fixed point
                tau = (s2 - 1.0f) / (float)c2;
                prev = c2;
            }
        }
        #pragma unroll 4
        for (int i = 0; i < 32; ++i) {
            const int k = g + 32 * i;
            Srow[k] = fmaxf(Srow[k] - tau, 0.f);
        }
    }
    __syncthreads();

    // ---- P @ V ----
    const int qi = tid & 15;
    const int eg = tid >> 4;          // 0..31, each owns 4 e-values
    float acc[4] = {0.f, 0.f, 0.f, 0.f};
    for (int vt = 0; vt < 16; ++vt) {
        __syncthreads();
        for (int ch = tid; ch < 2048; ch += 512) {
            const int r = ch >> 5;
            const int c = (ch & 31) * 4;
            float4 v = reinterpret_cast<const float4*>(V + hbbase + (size_t)(vt * 64) * 128)[ch];
            KT[(c + 0) * 65 + r] = v.x;
            KT[(c + 1) * 65 + r] = v.y;
            KT[(c + 2) * 65 + r] = v.z;
            KT[(c + 3) * 65 + r] = v.w;
        }
        __syncthreads();
        #pragma unroll 8
        for (int kk = 0; kk < 64; ++kk) {
            const float p = S[qi * SSTR + vt * 64 + kk];
            #pragma unroll
            for (int j = 0; j < 4; ++j)
                acc[j] += p * KT[(eg * 4 + j) * 65 + kk];
        }
    }
    const float gsel = sel[b * 8 + h];
    float* orow = out + ((size_t)b * 1024 + (t0 + qi)) * 128 + eg * 4;
    #pragma unroll
    for (int j = 0; j < 4; ++j)
        atomicAdd(&orow[j], gsel * acc[j]);
}

extern "C" void kernel_launch(void* const* d_in, const int* in_sizes, int n_in,
                              void* d_out, int out_size, void* d_ws, size_t ws_size,
                              hipStream_t stream) {
    (void)in_sizes; (void)n_in; (void)ws_size;
    const float* x   = (const float*)d_in[0];
    const int* mask  = (const int*)d_in[1];
    const float* wq  = (const float*)d_in[2];
    const float* wk  = (const float*)d_in[3];
    const float* wv  = (const float*)d_in[4];
    const float* wsl = (const float*)d_in[5];
    const float* bsl = (const float*)d_in[6];
    float* out = (float*)d_out;

    // workspace layout: sel (256 B, padded to 4 KB) | Q | K | V  (~100.7 MB)
    float* sel = (float*)d_ws;
    float* Qb  = (float*)((char*)d_ws + 4096);
    float* Kb  = Qb + (size_t)8 * 8 * 1024 * 128;
    float* Vb  = Kb + (size_t)8 * 8 * 1024 * 128;

    hipMemsetAsync(d_out, 0, (size_t)out_size * sizeof(float), stream);
    proj_kernel<<<dim3(512, 12), 256, 0, stream>>>(x, wq, wk, wv, Qb, Kb, Vb);
    sel_kernel<<<8, 1024, 0, stream>>>(x, wsl, bsl, sel);
    attn_kernel<<<4096, 512, 0, stream>>>(Qb, Kb, Vb, mask, sel, out);
}

// Round 2
// 531.005 us; speedup vs baseline: 4.2409x; 4.2409x over previous
//
#include <hip/hip_runtime.h>
#include <hip/hip_bf16.h>
#include <math.h>

#define SCALE 0.08838834764831845f  // 1/sqrt(128)

using short8 = __attribute__((ext_vector_type(8))) short;
using f32x4  = __attribute__((ext_vector_type(4))) float;
typedef unsigned long long u64;

// ---------------- projection kernel ----------------
// grid (512, 12), block 256. Q,K row-major bf16 [hb][t][128]; V transposed bf16 [hb][e][1024].
__global__ __launch_bounds__(256)
void proj_kernel(const float* __restrict__ x,
                 const float* __restrict__ wq,
                 const float* __restrict__ wk,
                 const float* __restrict__ wv,
                 __hip_bfloat16* __restrict__ Q,
                 __hip_bfloat16* __restrict__ K,
                 __hip_bfloat16* __restrict__ Vt) {
    __shared__ float xst[128 * 17];   // transposed x tile, padded stride (bank-conflict fix)
    const int tid = threadIdx.x;
    const int rblk = blockIdx.x * 16;              // x-row base (0..8191)
    for (int ch = tid; ch < 512; ch += 256) {      // 16 rows x 128 cols as float4
        const int r = ch >> 5;
        const int c = (ch & 31) * 4;
        float4 v = reinterpret_cast<const float4*>(x + (size_t)rblk * 128)[ch];
        xst[(c + 0) * 17 + r] = v.x;
        xst[(c + 1) * 17 + r] = v.y;
        xst[(c + 2) * 17 + r] = v.z;
        xst[(c + 3) * 17 + r] = v.w;
    }
    __syncthreads();
    const int c = blockIdx.y * 256 + tid;          // 0..3071
    const int m = c >> 10;                         // 0 q, 1 k, 2 v
    const int cc = c & 1023;
    const float* W = (m == 0) ? wq : (m == 1) ? wk : wv;
    float acc[16];
    #pragma unroll
    for (int i = 0; i < 16; ++i) acc[i] = 0.f;
    for (int kk = 0; kk < 128; ++kk) {
        const float w = W[kk * 1024 + cc];
        const float* xv = &xst[kk * 17];
        #pragma unroll
        for (int i = 0; i < 16; ++i) acc[i] += xv[i] * w;
    }
    const int h = cc >> 7, e = cc & 127;
    const int b = rblk >> 10, t = rblk & 1023;
    const size_t hbbase = (size_t)(h * 8 + b) * 131072;
    if (m == 0) {
        #pragma unroll
        for (int i = 0; i < 16; ++i)
            Q[hbbase + (size_t)(t + i) * 128 + e] = __float2bfloat16(acc[i] * SCALE);
    } else if (m == 1) {
        #pragma unroll
        for (int i = 0; i < 16; ++i)
            K[hbbase + (size_t)(t + i) * 128 + e] = __float2bfloat16(acc[i]);
    } else {
        #pragma unroll
        for (int i = 0; i < 16; ++i)
            Vt[hbbase + (size_t)e * 1024 + (t + i)] = __float2bfloat16(acc[i]);
    }
}

// ---------------- mask bit-pack kernel ----------------
// mask int32 [8][1024][1024] -> bits [8*1024 rows][16 u64 words]; bit=1 means masked.
__global__ __launch_bounds__(256)
void maskpack_kernel(const int* __restrict__ mask, u64* __restrict__ mp) {
    const int row = blockIdx.x * 4 + (threadIdx.x >> 6);
    const int l = threadIdx.x & 63;
    const int* m = mask + (size_t)row * 1024;
    #pragma unroll
    for (int c = 0; c < 16; ++c) {
        u64 bm = __ballot(m[c * 64 + l] != 0);
        if (l == 0) mp[(size_t)row * 16 + c] = bm;
    }
}

// ---------------- gating (sel) kernel ----------------
__global__ __launch_bounds__(1024)
void sel_kernel(const float* __restrict__ x, const float* __restrict__ wsl,
                const float* __restrict__ bsl, float* __restrict__ sel) {
    __shared__ float part[8][128];
    __shared__ float xm[128];
    __shared__ float lg[8];
    const int b = blockIdx.x;
    const int tid = threadIdx.x;
    const int e = tid & 127, tc = tid >> 7;
    float s = 0.f;
    for (int t = 0; t < 128; ++t)
        s += x[((size_t)b * 1024 + tc * 128 + t) * 128 + e];
    part[tc][e] = s;
    __syncthreads();
    if (tid < 128) {
        float tot = 0.f;
        #pragma unroll
        for (int i = 0; i < 8; ++i) tot += part[i][tid];
        xm[tid] = tot * (1.0f / 1024.0f);
    }
    __syncthreads();
    if (tid < 8) {
        float d = 0.f;
        for (int e2 = 0; e2 < 128; ++e2) d += xm[e2] * wsl[tid * 128 + e2];
        lg[tid] = d + bsl[tid];
    }
    __syncthreads();
    if (tid == 0) {
        float mx = lg[0];
        for (int hh = 1; hh < 8; ++hh) mx = fmaxf(mx, lg[hh]);
        float se = 0.f; float ex[8];
        for (int hh = 0; hh < 8; ++hh) { ex[hh] = expf(lg[hh] - mx); se += ex[hh]; }
        for (int hh = 0; hh < 8; ++hh) sel[b * 8 + hh] = ex[hh] / se;
    }
}

// ---------------- MFMA attention kernel ----------------
// grid 4096 = 64 (h,b) * 64 q-tiles of 16 rows; block 512 (8 waves).
// Wave w owns ktiles w*8..w*8+7 for QK^T (scores in regs) and e-tile w for PV.
__global__ __launch_bounds__(512, 4)
void attn_kernel(const __hip_bfloat16* __restrict__ Qb,
                 const __hip_bfloat16* __restrict__ Kb,
                 const __hip_bfloat16* __restrict__ Vtb,
                 const u64* __restrict__ mp,
                 const float* __restrict__ sel,
                 float* __restrict__ out) {
    __shared__ unsigned short Plds[16 * 1024];  // P bf16, chunk-XOR swizzled
    __shared__ float red_s[16][8];
    __shared__ float red_c[16][8];
    __shared__ float tauL[16];
    __shared__ int cntL[16];
    __shared__ int doneL;

    const int tid = threadIdx.x;
    const int w = tid >> 6;           // wave 0..7
    const int l = tid & 63;
    const int l15 = l & 15;
    const int lq = l >> 4;            // 0..3
    const int hb = (int)blockIdx.x >> 6;
    const int qt = (int)blockIdx.x & 63;
    const int h = hb >> 3, b = hb & 7;
    const int t0 = qt * 16;
    const size_t base = (size_t)hb * 131072;

    // ---- Q A-fragments (A: row=l&15, k=(l>>4)*8+j per 32-wide kfrag) ----
    short8 qa[4];
    {
        const unsigned short* qrow =
            (const unsigned short*)Qb + base + (size_t)(t0 + l15) * 128 + lq * 8;
        #pragma unroll
        for (int f = 0; f < 4; ++f)
            qa[f] = *reinterpret_cast<const short8*>(qrow + f * 32);
    }

    // ---- QK^T: scores in registers. sc[i][r] = S[q=lq*4+r][k=(w*8+i)*16+l15] ----
    f32x4 sc[8];
    #pragma unroll
    for (int i = 0; i < 8; ++i) {
        const int kt = w * 8 + i;
        const unsigned short* krow =
            (const unsigned short*)Kb + base + (size_t)(kt * 16 + l15) * 128 + lq * 8;
        f32x4 acc = {0.f, 0.f, 0.f, 0.f};
        #pragma unroll
        for (int f = 0; f < 4; ++f) {
            short8 kb = *reinterpret_cast<const short8*>(krow + f * 32);
            acc = __builtin_amdgcn_mfma_f32_16x16x32_bf16(qa[f], kb, acc, 0, 0, 0);
        }
        sc[i] = acc;
    }

    // ---- mask (bit=1 -> masked -> -1e30) ----
    const int rowbase = b * 1024 + t0;
    #pragma unroll
    for (int r = 0; r < 4; ++r) {
        const int q = lq * 4 + r;
        const u64* mrow = mp + (size_t)(rowbase + q) * 16 + w * 2;
        const u64 m0 = mrow[0], m1 = mrow[1];
        #pragma unroll
        for (int i = 0; i < 8; ++i) {
            const u64 mword = (i < 4) ? m0 : m1;
            const int bit = (i & 3) * 16 + l15;
            if ((mword >> bit) & 1ULL) sc[i][r] = -1e30f;
        }
    }

    // ---- sparsemax: Michelot fixed-point on register-resident scores ----
    float tau[4];
    {
        float s[4], c[4];
        #pragma unroll
        for (int r = 0; r < 4; ++r) {
            s[r] = 0.f; c[r] = 0.f;
            #pragma unroll
            for (int i = 0; i < 8; ++i) {
                const float z = sc[i][r];
                if (z > -1e29f) { s[r] += z; c[r] += 1.f; }
            }
        }
        #pragma unroll
        for (int mm = 1; mm < 16; mm <<= 1) {
            #pragma unroll
            for (int r = 0; r < 4; ++r) {
                s[r] += __shfl_xor(s[r], mm);
                c[r] += __shfl_xor(c[r], mm);
            }
        }
        if (l15 == 0) {
            #pragma unroll
            for (int r = 0; r < 4; ++r) {
                red_s[lq * 4 + r][w] = s[r];
                red_c[lq * 4 + r][w] = c[r];
            }
        }
    }
    __syncthreads();
    if (w == 0 && l < 16) {
        float s = 0.f, c = 0.f;
        #pragma unroll
        for (int j = 0; j < 8; ++j) { s += red_s[l][j]; c += red_c[l][j]; }
        const int ic = (int)c;
        tauL[l] = (ic > 0) ? (s - 1.f) / c : 3e38f;
        cntL[l] = ic;
    }
    __syncthreads();
    #pragma unroll
    for (int r = 0; r < 4; ++r) tau[r] = tauL[lq * 4 + r];

    for (int iter = 0; iter < 64; ++iter) {
        float s[4], c[4];
        #pragma unroll
        for (int r = 0; r < 4; ++r) {
            s[r] = 0.f; c[r] = 0.f;
            #pragma unroll
            for (int i = 0; i < 8; ++i) {
                const float z = sc[i][r];
                if (z > tau[r]) { s[r] += z; c[r] += 1.f; }
            }
        }
        #pragma unroll
        for (int mm = 1; mm < 16; mm <<= 1) {
            #pragma unroll
            for (int r = 0; r < 4; ++r) {
                s[r] += __shfl_xor(s[r], mm);
                c[r] += __shfl_xor(c[r], mm);
            }
        }
        if (l15 == 0) {
            #pragma unroll
            for (int r = 0; r < 4; ++r) {
                red_s[lq * 4 + r][w] = s[r];
                red_c[lq * 4 + r][w] = c[r];
            }
        }
        __syncthreads();
        if (w == 0) {
            int changed = 0;
            if (l < 16) {
                float s2 = 0.f, c2 = 0.f;
                #pragma unroll
                for (int j = 0; j < 8; ++j) { s2 += red_s[l][j]; c2 += red_c[l][j]; }
                const int nc = (int)c2;
                if (nc != cntL[l]) {
                    changed = 1;
                    cntL[l] = nc;
                    tauL[l] = (s2 - 1.f) / c2;
                }
            }
            const u64 bal = __ballot(changed);
            if (l == 0) doneL = (bal == 0ULL) ? 1 : 0;
        }
        __syncthreads();
        if (doneL) break;
        #pragma unroll
        for (int r = 0; r < 4; ++r) tau[r] = tauL[lq * 4 + r];
    }

    // ---- write P (bf16) to swizzled LDS ----
    #pragma unroll
    for (int r = 0; r < 4; ++r) {
        const int q = lq * 4 + r;
        #pragma unroll
        for (int i = 0; i < 8; ++i) {
            const int k = (w * 8 + i) * 16 + l15;
            const float p = fmaxf(sc[i][r] - tau[r], 0.f);
            const int ccn = k >> 3;
            const int scc = ccn ^ (q & 7);
            __hip_bfloat16 pb = __float2bfloat16(p);
            Plds[q * 1024 + scc * 8 + (k & 7)] = *reinterpret_cast<unsigned short*>(&pb);
        }
    }
    __syncthreads();

    // ---- P @ V : wave w computes e-tile w (cols w*16..w*16+15) over all k ----
    f32x4 o[4];
    #pragma unroll
    for (int u = 0; u < 4; ++u) o[u] = (f32x4){0.f, 0.f, 0.f, 0.f};
    const unsigned short* vrow =
        (const unsigned short*)Vtb + base + (size_t)(w * 16 + l15) * 1024 + lq * 8;
    #pragma unroll 2
    for (int gg = 0; gg < 8; ++gg) {
        #pragma unroll
        for (int u = 0; u < 4; ++u) {
            const int kf = gg * 4 + u;              // 0..31 (32-wide K slabs)
            const int ccn = kf * 4 + lq;
            const int scc = ccn ^ (l15 & 7);
            short8 pa = *reinterpret_cast<const short8*>(&Plds[l15 * 1024 + scc * 8]);
            short8 vb = *reinterpret_cast<const short8*>(vrow + kf * 32);
            o[u] = __builtin_amdgcn_mfma_f32_16x16x32_bf16(pa, vb, o[u], 0, 0, 0);
        }
    }
    const f32x4 osum = (o[0] + o[1]) + (o[2] + o[3]);
    const float gsel = sel[b * 8 + h];
    #pragma unroll
    for (int r = 0; r < 4; ++r) {
        atomicAdd(&out[(size_t)(b * 1024 + t0 + lq * 4 + r) * 128 + w * 16 + l15],
                  gsel * osum[r]);
    }
}

extern "C" void kernel_launch(void* const* d_in, const int* in_sizes, int n_in,
                              void* d_out, int out_size, void* d_ws, size_t ws_size,
                              hipStream_t stream) {
    (void)in_sizes; (void)n_in; (void)ws_size;
    const float* x   = (const float*)d_in[0];
    const int* mask  = (const int*)d_in[1];
    const float* wq  = (const float*)d_in[2];
    const float* wk  = (const float*)d_in[3];
    const float* wv  = (const float*)d_in[4];
    const float* wsl = (const float*)d_in[5];
    const float* bsl = (const float*)d_in[6];
    float* out = (float*)d_out;

    // ws layout: sel 1KB | maskp 1MB | Q 16MB | K 16MB | Vt 16MB  (~51 MB)
    float* sel = (float*)d_ws;
    u64* mp = (u64*)((char*)d_ws + 1024);
    __hip_bfloat16* Qb  = (__hip_bfloat16*)((char*)d_ws + 1024 + 1048576);
    __hip_bfloat16* Kb  = Qb + (size_t)8388608;
    __hip_bfloat16* Vtb = Kb + (size_t)8388608;

    hipMemsetAsync(d_out, 0, (size_t)out_size * sizeof(float), stream);
    proj_kernel<<<dim3(512, 12), 256, 0, stream>>>(x, wq, wk, wv, Qb, Kb, Vtb);
    maskpack_kernel<<<2048, 256, 0, stream>>>(mask, mp);
    sel_kernel<<<8, 1024, 0, stream>>>(x, wsl, bsl, sel);
    attn_kernel<<<4096, 512, 0, stream>>>(Qb, Kb, Vtb, mp, sel, out);
}

// Round 4
// 365.448 us; speedup vs baseline: 6.1622x; 1.4530x over previous
//
#include <hip/hip_runtime.h>
#include <hip/hip_bf16.h>
#include <math.h>

#define SCALE 0.08838834764831845f  // 1/sqrt(128)

using short8  = __attribute__((ext_vector_type(8))) short;
using short4v = __attribute__((ext_vector_type(4))) short;
using f32x4   = __attribute__((ext_vector_type(4))) float;
typedef unsigned long long u64;
typedef unsigned short ushort_t;

static __device__ __forceinline__ ushort_t bf16_of(float f) {
    __hip_bfloat16 h = __float2bfloat16(f);
    return *reinterpret_cast<ushort_t*>(&h);
}

// ---------------- prep: x -> bf16 ----------------
// grid 1024, block 256: 262144 float4 groups
__global__ __launch_bounds__(256)
void prep_x(const float* __restrict__ x, ushort_t* __restrict__ xb) {
    const int i = blockIdx.x * 256 + threadIdx.x;
    float4 v = reinterpret_cast<const float4*>(x)[i];
    short4v o;
    o.x = (short)bf16_of(v.x); o.y = (short)bf16_of(v.y);
    o.z = (short)bf16_of(v.z); o.w = (short)bf16_of(v.w);
    reinterpret_cast<short4v*>(xb)[i] = o;
}

// ---------------- prep: W -> bf16, transposed [3072][128] ----------------
// grid 48 (16 per matrix), block 256. Each W is a separate [128][1024] array.
__global__ __launch_bounds__(256)
void prep_w(const float* __restrict__ wq, const float* __restrict__ wk,
            const float* __restrict__ wv, ushort_t* __restrict__ Wt) {
    __shared__ float tile[64][129];
    const int mat = blockIdx.x >> 4;
    const int n0 = (blockIdx.x & 15) * 64;
    const float* W = (mat == 0) ? wq : (mat == 1) ? wk : wv;
    const int tid = threadIdx.x;
    for (int idx = tid; idx < 8192; idx += 256) {
        const int k = idx >> 6, c = idx & 63;
        tile[c][k] = W[(size_t)k * 1024 + n0 + c];   // FIX: per-matrix stride 1024
    }
    __syncthreads();
    for (int idx = tid; idx < 8192; idx += 256) {
        const int c = idx >> 7, k = idx & 127;
        Wt[(size_t)(mat * 1024 + n0 + c) * 128 + k] = bf16_of(tile[c][k]);
    }
}

// ---------------- MFMA projection GEMM ----------------
// grid (128, 48), block 256 (4 waves). mat = blockIdx.y>>4 (0 Q,1 K,2 V).
__global__ __launch_bounds__(256)
void proj_gemm(const ushort_t* __restrict__ xb, const ushort_t* __restrict__ Wt,
               ushort_t* __restrict__ Q, ushort_t* __restrict__ K,
               ushort_t* __restrict__ Vt) {
    const int tid = threadIdx.x;
    const int w = tid >> 6, l = tid & 63;
    const int l15 = l & 15, lq = l >> 4;
    const int m0 = blockIdx.x * 64;
    const int nb = blockIdx.y;
    const int mat = nb >> 4;
    const int n0 = (nb & 15) * 64;
    const int b = m0 >> 10;

    if (mat < 2) {
        short8 af[4][4];
        #pragma unroll
        for (int at = 0; at < 4; ++at) {
            const ushort_t* ar = xb + (size_t)(m0 + at * 16 + l15) * 128 + lq * 8;
            #pragma unroll
            for (int f = 0; f < 4; ++f)
                af[at][f] = *reinterpret_cast<const short8*>(ar + f * 32);
        }
        const int ng = n0 + w * 16 + l15;
        const ushort_t* br = Wt + (size_t)(mat * 1024 + ng) * 128 + lq * 8;
        short8 bf[4];
        #pragma unroll
        for (int f = 0; f < 4; ++f)
            bf[f] = *reinterpret_cast<const short8*>(br + f * 32);
        f32x4 acc[4];
        #pragma unroll
        for (int at = 0; at < 4; ++at) acc[at] = (f32x4){0.f, 0.f, 0.f, 0.f};
        #pragma unroll
        for (int at = 0; at < 4; ++at)
            #pragma unroll
            for (int f = 0; f < 4; ++f)
                acc[at] = __builtin_amdgcn_mfma_f32_16x16x32_bf16(af[at][f], bf[f], acc[at], 0, 0, 0);
        const int h = ng >> 7, e = ng & 127;
        ushort_t* O = (mat == 0) ? Q : K;
        const float scl = (mat == 0) ? SCALE : 1.0f;
        const size_t obase = (size_t)(h * 8 + b) * 131072 + e;
        #pragma unroll
        for (int at = 0; at < 4; ++at)
            #pragma unroll
            for (int r = 0; r < 4; ++r) {
                const int t = (m0 & 1023) + at * 16 + lq * 4 + r;
                O[obase + (size_t)t * 128] = bf16_of(acc[at][r] * scl);
            }
    } else {
        short8 af[4][4];
        #pragma unroll
        for (int at = 0; at < 4; ++at) {
            const ushort_t* ar = Wt + (size_t)(2048 + n0 + at * 16 + l15) * 128 + lq * 8;
            #pragma unroll
            for (int f = 0; f < 4; ++f)
                af[at][f] = *reinterpret_cast<const short8*>(ar + f * 32);
        }
        const ushort_t* br = xb + (size_t)(m0 + w * 16 + l15) * 128 + lq * 8;
        short8 bf[4];
        #pragma unroll
        for (int f = 0; f < 4; ++f)
            bf[f] = *reinterpret_cast<const short8*>(br + f * 32);
        f32x4 acc[4];
        #pragma unroll
        for (int at = 0; at < 4; ++at) acc[at] = (f32x4){0.f, 0.f, 0.f, 0.f};
        #pragma unroll
        for (int at = 0; at < 4; ++at)
            #pragma unroll
            for (int f = 0; f < 4; ++f)
                acc[at] = __builtin_amdgcn_mfma_f32_16x16x32_bf16(af[at][f], bf[f], acc[at], 0, 0, 0);
        const int t = (m0 & 1023) + w * 16 + l15;
        #pragma unroll
        for (int at = 0; at < 4; ++at)
            #pragma unroll
            for (int r = 0; r < 4; ++r) {
                const int eg = n0 + at * 16 + lq * 4 + r;
                const int h = eg >> 7, e = eg & 127;
                Vt[(size_t)(h * 8 + b) * 131072 + (size_t)e * 1024 + t] = bf16_of(acc[at][r]);
            }
    }
}

// ---------------- mask bit-pack kernel ----------------
__global__ __launch_bounds__(256)
void maskpack_kernel(const int* __restrict__ mask, u64* __restrict__ mp) {
    const int row = blockIdx.x * 4 + (threadIdx.x >> 6);
    const int l = threadIdx.x & 63;
    const int* m = mask + (size_t)row * 1024;
    #pragma unroll
    for (int c = 0; c < 16; ++c) {
        u64 bm = __ballot(m[c * 64 + l] != 0);
        if (l == 0) mp[(size_t)row * 16 + c] = bm;
    }
}

// ---------------- gating (sel) kernel ----------------
__global__ __launch_bounds__(1024)
void sel_kernel(const float* __restrict__ x, const float* __restrict__ wsl,
                const float* __restrict__ bsl, float* __restrict__ sel) {
    __shared__ float part[8][128];
    __shared__ float xm[128];
    __shared__ float lg[8];
    const int b = blockIdx.x;
    const int tid = threadIdx.x;
    const int e = tid & 127, tc = tid >> 7;
    float s = 0.f;
    for (int t = 0; t < 128; ++t)
        s += x[((size_t)b * 1024 + tc * 128 + t) * 128 + e];
    part[tc][e] = s;
    __syncthreads();
    if (tid < 128) {
        float tot = 0.f;
        #pragma unroll
        for (int i = 0; i < 8; ++i) tot += part[i][tid];
        xm[tid] = tot * (1.0f / 1024.0f);
    }
    __syncthreads();
    if (tid < 8) {
        float d = 0.f;
        for (int e2 = 0; e2 < 128; ++e2) d += xm[e2] * wsl[tid * 128 + e2];
        lg[tid] = d + bsl[tid];
    }
    __syncthreads();
    if (tid == 0) {
        float mx = lg[0];
        for (int hh = 1; hh < 8; ++hh) mx = fmaxf(mx, lg[hh]);
        float se = 0.f; float ex[8];
        for (int hh = 0; hh < 8; ++hh) { ex[hh] = expf(lg[hh] - mx); se += ex[hh]; }
        for (int hh = 0; hh < 8; ++hh) sel[b * 8 + hh] = ex[hh] / se;
    }
}

// ---------------- MFMA attention kernel, wave-local sparsemax ----------------
// grid 4096 = 64 (h,b) * 64 q-tiles of 16 rows; block 512 (8 waves).
__global__ __launch_bounds__(512, 2)
void attn_kernel(const ushort_t* __restrict__ Qb, const ushort_t* __restrict__ Kb,
                 const ushort_t* __restrict__ Vtb, const u64* __restrict__ mp,
                 const float* __restrict__ sel, float* __restrict__ out) {
    __shared__ float S[16 * 1024];                       // 64 KB; P bf16 aliases low half
    ushort_t* Pl = reinterpret_cast<ushort_t*>(S);

    const int tid = threadIdx.x;
    const int w = tid >> 6, l = tid & 63;
    const int l15 = l & 15, lq = l >> 4;
    const int hb = (int)blockIdx.x >> 6;
    const int qt = (int)blockIdx.x & 63;
    const int h = hb >> 3, b = hb & 7;
    const int t0 = qt * 16;
    const size_t base = (size_t)hb * 131072;

    // ---- Q A-frags (row=l15, k=lq*8+f*32..) ----
    short8 qa[4];
    {
        const ushort_t* qrp = Qb + base + (size_t)(t0 + l15) * 128 + lq * 8;
        #pragma unroll
        for (int f = 0; f < 4; ++f)
            qa[f] = *reinterpret_cast<const short8*>(qrp + f * 32);
    }

    // ---- QK^T: sc[i][r] = S[q=lq*4+r][k=(w*8+i)*16+l15] ----
    f32x4 sc[8];
    #pragma unroll
    for (int i = 0; i < 8; ++i) {
        const int kt = w * 8 + i;
        const ushort_t* krow = Kb + base + (size_t)(kt * 16 + l15) * 128 + lq * 8;
        f32x4 acc = {0.f, 0.f, 0.f, 0.f};
        #pragma unroll
        for (int f = 0; f < 4; ++f) {
            short8 kb = *reinterpret_cast<const short8*>(krow + f * 32);
            acc = __builtin_amdgcn_mfma_f32_16x16x32_bf16(qa[f], kb, acc, 0, 0, 0);
        }
        sc[i] = acc;
    }

    // ---- mask ----
    const int rowbase = b * 1024 + t0;
    #pragma unroll
    for (int r = 0; r < 4; ++r) {
        const int q = lq * 4 + r;
        const u64* mrow = mp + (size_t)(rowbase + q) * 16 + w * 2;
        const u64 m0 = mrow[0], m1 = mrow[1];
        #pragma unroll
        for (int i = 0; i < 8; ++i) {
            const u64 mword = (i < 4) ? m0 : m1;
            const int bit = (i & 3) * 16 + l15;
            if ((mword >> bit) & 1ULL) sc[i][r] = -1e30f;
        }
    }

    // ---- S store (f32, chunk-swizzled: cp = c ^ ((c>>3)&7) ^ (q&7)) ----
    #pragma unroll
    for (int r = 0; r < 4; ++r) {
        const int q = lq * 4 + r;
        #pragma unroll
        for (int i = 0; i < 8; ++i) {
            const int c = (w * 8 + i) * 4 + (l15 >> 2);
            const int cp = c ^ ((c >> 3) & 7) ^ (q & 7);
            S[q * 1024 + cp * 4 + (l15 & 3)] = sc[i][r];
        }
    }
    __syncthreads();

    // ---- transpose read: lane owns 32 values of row qrow = 2w + (l&1) ----
    const int qrow = 2 * w + (l & 1);
    const int lh = l >> 1;
    float z[32];
    #pragma unroll
    for (int j = 0; j < 8; ++j) {
        const int c = lh + 32 * j;
        const int cp = c ^ ((c >> 3) & 7) ^ (qrow & 7);
        float4 v = *reinterpret_cast<const float4*>(&S[qrow * 1024 + cp * 4]);
        z[4 * j + 0] = v.x; z[4 * j + 1] = v.y;
        z[4 * j + 2] = v.z; z[4 * j + 3] = v.w;
    }
    __syncthreads();   // all S reads done before P overwrites the buffer

    // ---- Michelot sparsemax, wave-local (no barriers) ----
    float s0 = 0.f, c0 = 0.f;
    #pragma unroll
    for (int k = 0; k < 32; ++k) {
        const float zz = z[k];
        if (zz > -1e29f) { s0 += zz; c0 += 1.f; }
    }
    #pragma unroll
    for (int mm = 2; mm < 64; mm <<= 1) {
        s0 += __shfl_xor(s0, mm);
        c0 += __shfl_xor(c0, mm);
    }
    float tau = (c0 > 0.f) ? (s0 - 1.f) / c0 : 3e38f;
    float prev = c0;
    for (int it = 0; it < 64; ++it) {
        float s2 = 0.f, c2 = 0.f;
        #pragma unroll
        for (int k = 0; k < 32; ++k) {
            const float zz = z[k];
            if (zz > tau) { s2 += zz; c2 += 1.f; }
        }
        #pragma unroll
        for (int mm = 2; mm < 64; mm <<= 1) {
            s2 += __shfl_xor(s2, mm);
            c2 += __shfl_xor(c2, mm);
        }
        const int stable = (c2 == prev) ? 1 : 0;
        if (__all(stable)) break;
        if (!stable) { tau = (s2 - 1.f) / c2; prev = c2; }
    }

    // ---- P = max(z - tau, 0) -> bf16, swizzled chunks (kc8 ^ (q&7)) ----
    #pragma unroll
    for (int j = 0; j < 8; ++j) {
        const int c = lh + 32 * j;
        short4v pk;
        pk.x = (short)bf16_of(fmaxf(z[4 * j + 0] - tau, 0.f));
        pk.y = (short)bf16_of(fmaxf(z[4 * j + 1] - tau, 0.f));
        pk.z = (short)bf16_of(fmaxf(z[4 * j + 2] - tau, 0.f));
        pk.w = (short)bf16_of(fmaxf(z[4 * j + 3] - tau, 0.f));
        const int ea = qrow * 1024 + (((c >> 1) ^ (qrow & 7)) << 3) + ((c & 1) << 2);
        *reinterpret_cast<short4v*>(&Pl[ea]) = pk;
    }
    __syncthreads();

    // ---- P @ V : wave w -> e-tile w ----
    f32x4 o[4];
    #pragma unroll
    for (int u = 0; u < 4; ++u) o[u] = (f32x4){0.f, 0.f, 0.f, 0.f};
    const ushort_t* vrow = Vtb + base + (size_t)(w * 16 + l15) * 1024 + lq * 8;
    #pragma unroll 2
    for (int gg = 0; gg < 8; ++gg) {
        #pragma unroll
        for (int u = 0; u < 4; ++u) {
            const int kf = gg * 4 + u;
            const int kc8 = kf * 4 + lq;
            short8 pa = *reinterpret_cast<const short8*>(&Pl[l15 * 1024 + (kc8 ^ (l15 & 7)) * 8]);
            short8 vb = *reinterpret_cast<const short8*>(vrow + kf * 32);
            o[u] = __builtin_amdgcn_mfma_f32_16x16x32_bf16(pa, vb, o[u], 0, 0, 0);
        }
    }
    const f32x4 osum = (o[0] + o[1]) + (o[2] + o[3]);
    const float gsel = sel[b * 8 + h];
    #pragma unroll
    for (int r = 0; r < 4; ++r) {
        atomicAdd(&out[(size_t)(b * 1024 + t0 + lq * 4 + r) * 128 + w * 16 + l15],
                  gsel * osum[r]);
    }
}

extern "C" void kernel_launch(void* const* d_in, const int* in_sizes, int n_in,
                              void* d_out, int out_size, void* d_ws, size_t ws_size,
                              hipStream_t stream) {
    (void)in_sizes; (void)n_in; (void)ws_size;
    const float* x   = (const float*)d_in[0];
    const int* mask  = (const int*)d_in[1];
    const float* wq  = (const float*)d_in[2];
    const float* wk  = (const float*)d_in[3];
    const float* wv  = (const float*)d_in[4];
    const float* wsl = (const float*)d_in[5];
    const float* bsl = (const float*)d_in[6];
    float* out = (float*)d_out;

    // ws: sel 4KB | mp 1MB | xb 2MB | Wt 768KB | Q 16MB | K 16MB | Vt 16MB
    char* wsc = (char*)d_ws;
    float*    sel = (float*)wsc;
    u64*      mp  = (u64*)(wsc + 4096);
    ushort_t* xb  = (ushort_t*)(wsc + 4096 + 1048576);
    ushort_t* Wt  = (ushort_t*)(wsc + 4096 + 1048576 + 2097152);
    ushort_t* Qb  = (ushort_t*)(wsc + 4096 + 1048576 + 2097152 + 786432);
    ushort_t* Kb  = Qb + (size_t)8388608;
    ushort_t* Vtb = Kb + (size_t)8388608;

    hipMemsetAsync(d_out, 0, (size_t)out_size * sizeof(float), stream);
    prep_x<<<1024, 256, 0, stream>>>(x, xb);
    prep_w<<<48, 256, 0, stream>>>(wq, wk, wv, Wt);
    proj_gemm<<<dim3(128, 48), 256, 0, stream>>>(xb, Wt, Qb, Kb, Vtb);
    maskpack_kernel<<<2048, 256, 0, stream>>>(mask, mp);
    sel_kernel<<<8, 1024, 0, stream>>>(x, wsl, bsl, sel);
    attn_kernel<<<4096, 512, 0, stream>>>(Qb, Kb, Vtb, mp, sel, out);
}

// Round 6
// 303.854 us; speedup vs baseline: 7.4113x; 1.2027x over previous
//
#include <hip/hip_runtime.h>
#include <hip/hip_bf16.h>
#include <math.h>

#define SCALE 0.08838834764831845f  // 1/sqrt(128)

using short8  = __attribute__((ext_vector_type(8))) short;
using short4v = __attribute__((ext_vector_type(4))) short;
using us4     = __attribute__((ext_vector_type(4))) unsigned short;
using f32x4   = __attribute__((ext_vector_type(4))) float;
typedef unsigned long long u64;
typedef unsigned short ushort_t;

static __device__ __forceinline__ ushort_t bf16_of(float f) {
    __hip_bfloat16 h = __float2bfloat16(f);
    return *reinterpret_cast<ushort_t*>(&h);
}
static __device__ __forceinline__ float f_of_bf16(unsigned int u) {
    union { unsigned int i; float f; } v; v.i = u << 16; return v.f;
}

// ---------------- fused prep kernel ----------------
// grid 3120 x 256:
//   [0,1024)    : x -> bf16
//   [1024,1072) : W -> bf16 transposed [3072][128]
//   [1072,3120) : mask bit-pack (8192 rows x 16 u64)
__global__ __launch_bounds__(256)
void prep_all(const float* __restrict__ x, ushort_t* __restrict__ xb,
              const float* __restrict__ wq, const float* __restrict__ wk,
              const float* __restrict__ wv, ushort_t* __restrict__ Wt,
              const int* __restrict__ mask, u64* __restrict__ mp) {
    __shared__ float tile[64][129];
    const int bx = blockIdx.x;
    const int tid = threadIdx.x;
    if (bx < 1024) {
        const int i = bx * 256 + tid;
        float4 v = reinterpret_cast<const float4*>(x)[i];
        short4v o;
        o.x = (short)bf16_of(v.x); o.y = (short)bf16_of(v.y);
        o.z = (short)bf16_of(v.z); o.w = (short)bf16_of(v.w);
        reinterpret_cast<short4v*>(xb)[i] = o;
    } else if (bx < 1072) {
        const int wb = bx - 1024;
        const int mat = wb >> 4;
        const int n0 = (wb & 15) * 64;
        const float* W = (mat == 0) ? wq : (mat == 1) ? wk : wv;
        for (int idx = tid; idx < 8192; idx += 256) {
            const int k = idx >> 6, c = idx & 63;
            tile[c][k] = W[(size_t)k * 1024 + n0 + c];
        }
        __syncthreads();
        for (int idx = tid; idx < 8192; idx += 256) {
            const int c = idx >> 7, k = idx & 127;
            Wt[(size_t)(mat * 1024 + n0 + c) * 128 + k] = bf16_of(tile[c][k]);
        }
    } else {
        const int mb = bx - 1072;
        const int row = mb * 4 + (tid >> 6);
        const int l = tid & 63;
        const int* m = mask + (size_t)row * 1024;
        #pragma unroll
        for (int c = 0; c < 16; ++c) {
            u64 bm = __ballot(m[c * 64 + l] != 0);
            if (l == 0) mp[(size_t)row * 16 + c] = bm;
        }
    }
}

// ---------------- MFMA projection GEMM ----------------
// grid (128, 48), block 256 (4 waves). mat = blockIdx.y>>4 (0 Q,1 K,2 V).
// All outputs row-major bf16 [hb][t][128]; Q pre-scaled.
__global__ __launch_bounds__(256)
void proj_gemm(const ushort_t* __restrict__ xb, const ushort_t* __restrict__ Wt,
               ushort_t* __restrict__ Q, ushort_t* __restrict__ K,
               ushort_t* __restrict__ V) {
    const int tid = threadIdx.x;
    const int w = tid >> 6, l = tid & 63;
    const int l15 = l & 15, lq = l >> 4;
    const int m0 = blockIdx.x * 64;
    const int nb = blockIdx.y;
    const int mat = nb >> 4;
    const int n0 = (nb & 15) * 64;
    const int b = m0 >> 10;

    short8 af[4][4];
    #pragma unroll
    for (int at = 0; at < 4; ++at) {
        const ushort_t* ar = xb + (size_t)(m0 + at * 16 + l15) * 128 + lq * 8;
        #pragma unroll
        for (int f = 0; f < 4; ++f)
            af[at][f] = *reinterpret_cast<const short8*>(ar + f * 32);
    }
    const int ng = n0 + w * 16 + l15;
    const ushort_t* br = Wt + (size_t)(mat * 1024 + ng) * 128 + lq * 8;
    short8 bf[4];
    #pragma unroll
    for (int f = 0; f < 4; ++f)
        bf[f] = *reinterpret_cast<const short8*>(br + f * 32);
    f32x4 acc[4];
    #pragma unroll
    for (int at = 0; at < 4; ++at) acc[at] = (f32x4){0.f, 0.f, 0.f, 0.f};
    #pragma unroll
    for (int at = 0; at < 4; ++at)
        #pragma unroll
        for (int f = 0; f < 4; ++f)
            acc[at] = __builtin_amdgcn_mfma_f32_16x16x32_bf16(af[at][f], bf[f], acc[at], 0, 0, 0);

    const int h = ng >> 7, e = ng & 127;
    ushort_t* O = (mat == 0) ? Q : (mat == 1) ? K : V;
    const float scl = (mat == 0) ? SCALE : 1.0f;
    const size_t obase = (size_t)(h * 8 + b) * 131072 + e;
    #pragma unroll
    for (int at = 0; at < 4; ++at)
        #pragma unroll
        for (int r = 0; r < 4; ++r) {
            const int t = (m0 & 1023) + at * 16 + lq * 4 + r;
            O[obase + (size_t)t * 128] = bf16_of(acc[at][r] * scl);
        }
}

// ---------------- gating (sel) kernel ----------------
__global__ __launch_bounds__(1024)
void sel_kernel(const float* __restrict__ x, const float* __restrict__ wsl,
                const float* __restrict__ bsl, float* __restrict__ sel) {
    __shared__ float part[8][128];
    __shared__ float xm[128];
    __shared__ float lg[8];
    const int b = blockIdx.x;
    const int tid = threadIdx.x;
    const int e = tid & 127, tc = tid >> 7;
    float s = 0.f;
    for (int t = 0; t < 128; ++t)
        s += x[((size_t)b * 1024 + tc * 128 + t) * 128 + e];
    part[tc][e] = s;
    __syncthreads();
    if (tid < 128) {
        float tot = 0.f;
        #pragma unroll
        for (int i = 0; i < 8; ++i) tot += part[i][tid];
        xm[tid] = tot * (1.0f / 1024.0f);
    }
    __syncthreads();
    if (tid < 8) {
        float d = 0.f;
        for (int e2 = 0; e2 < 128; ++e2) d += xm[e2] * wsl[tid * 128 + e2];
        lg[tid] = d + bsl[tid];
    }
    __syncthreads();
    if (tid == 0) {
        float mx = lg[0];
        for (int hh = 1; hh < 8; ++hh) mx = fmaxf(mx, lg[hh]);
        float se = 0.f; float ex[8];
        for (int hh = 0; hh < 8; ++hh) { ex[hh] = expf(lg[hh] - mx); se += ex[hh]; }
        for (int hh = 0; hh < 8; ++hh) sel[b * 8 + hh] = ex[hh] / se;
    }
}

// ---------------- MFMA attention: Michelot sparsemax + sparse PV ----------------
// grid 4096 = 64 (h,b) * 64 q-tiles of 16 rows; block 512 (8 waves).
__global__ __launch_bounds__(512, 2)
void attn_kernel(const ushort_t* __restrict__ Qb, const ushort_t* __restrict__ Kb,
                 const ushort_t* __restrict__ Vb, const u64* __restrict__ mp,
                 const float* __restrict__ sel, float* __restrict__ out) {
    __shared__ float S[16 * 1024];   // 64 KB; support list aliases it later
    __shared__ int cnt[16];
    unsigned int* list = reinterpret_cast<unsigned int*>(S);

    const int tid = threadIdx.x;
    const int w = tid >> 6, l = tid & 63;
    const int l15 = l & 15, lq = l >> 4;
    const int hb = (int)blockIdx.x >> 6;
    const int qt = (int)blockIdx.x & 63;
    const int h = hb >> 3, b = hb & 7;
    const int t0 = qt * 16;
    const size_t base = (size_t)hb * 131072;

    if (tid < 16) cnt[tid] = 0;

    // ---- Q A-frags ----
    short8 qa[4];
    {
        const ushort_t* qrp = Qb + base + (size_t)(t0 + l15) * 128 + lq * 8;
        #pragma unroll
        for (int f = 0; f < 4; ++f)
            qa[f] = *reinterpret_cast<const short8*>(qrp + f * 32);
    }

    // ---- QK^T: sc[i][r] = S[q=lq*4+r][k=(w*8+i)*16+l15] ----
    f32x4 sc[8];
    #pragma unroll
    for (int i = 0; i < 8; ++i) {
        const int kt = w * 8 + i;
        const ushort_t* krow = Kb + base + (size_t)(kt * 16 + l15) * 128 + lq * 8;
        f32x4 acc = {0.f, 0.f, 0.f, 0.f};
        #pragma unroll
        for (int f = 0; f < 4; ++f) {
            short8 kb = *reinterpret_cast<const short8*>(krow + f * 32);
            acc = __builtin_amdgcn_mfma_f32_16x16x32_bf16(qa[f], kb, acc, 0, 0, 0);
        }
        sc[i] = acc;
    }

    // ---- mask (bit=1 -> -1e30) ----
    const int rowbase = b * 1024 + t0;
    #pragma unroll
    for (int r = 0; r < 4; ++r) {
        const int q = lq * 4 + r;
        const u64* mrow = mp + (size_t)(rowbase + q) * 16 + w * 2;
        const u64 m0 = mrow[0], m1 = mrow[1];
        #pragma unroll
        for (int i = 0; i < 8; ++i) {
            const u64 mword = (i < 4) ? m0 : m1;
            const int bit = (i & 3) * 16 + l15;
            if ((mword >> bit) & 1ULL) sc[i][r] = -1e30f;
        }
    }

    // ---- S store (f32, chunk-swizzled) ----
    #pragma unroll
    for (int r = 0; r < 4; ++r) {
        const int q = lq * 4 + r;
        #pragma unroll
        for (int i = 0; i < 8; ++i) {
            const int c = (w * 8 + i) * 4 + (l15 >> 2);
            const int cp = c ^ ((c >> 3) & 7) ^ (q & 7);
            S[q * 1024 + cp * 4 + (l15 & 3)] = sc[i][r];
        }
    }
    __syncthreads();

    // ---- transpose read: lane owns 32 vals of row qrow=2w+(l&1); z[4j+m] = col 4*lh+128*j+m ----
    const int qrow = 2 * w + (l & 1);
    const int lh = l >> 1;
    float z[32];
    #pragma unroll
    for (int j = 0; j < 8; ++j) {
        const int c = lh + 32 * j;
        const int cp = c ^ ((c >> 3) & 7) ^ (qrow & 7);
        float4 v = *reinterpret_cast<const float4*>(&S[qrow * 1024 + cp * 4]);
        z[4 * j + 0] = v.x; z[4 * j + 1] = v.y;
        z[4 * j + 2] = v.z; z[4 * j + 3] = v.w;
    }
    __syncthreads();   // S reads done before list overwrites the buffer

    // ---- Michelot sparsemax, wave-local (round-4-proven exact path) ----
    float s0 = 0.f, c0 = 0.f;
    #pragma unroll
    for (int k = 0; k < 32; ++k) {
        const float zz = z[k];
        if (zz > -1e29f) { s0 += zz; c0 += 1.f; }
    }
    #pragma unroll
    for (int mm = 2; mm < 64; mm <<= 1) {
        s0 += __shfl_xor(s0, mm);
        c0 += __shfl_xor(c0, mm);
    }
    float tau = (c0 > 0.f) ? (s0 - 1.f) / c0 : 3e38f;
    float prev = c0;
    for (int it = 0; it < 64; ++it) {
        float s2 = 0.f, c2 = 0.f;
        #pragma unroll
        for (int k = 0; k < 32; ++k) {
            const float zz = z[k];
            if (zz > tau) { s2 += zz; c2 += 1.f; }
        }
        #pragma unroll
        for (int mm = 2; mm < 64; mm <<= 1) {
            s2 += __shfl_xor(s2, mm);
            c2 += __shfl_xor(c2, mm);
        }
        const int stable = (c2 == prev) ? 1 : 0;
        if (__all(stable)) break;
        if (!stable) { tau = (s2 - 1.f) / c2; prev = c2; }
    }

    // ---- compact support (k, p-bf16) into list (fully unrolled: static z idx) ----
    #pragma unroll
    for (int j = 0; j < 32; ++j) {
        const float p = z[j] - tau;
        if (p > 0.f) {
            const int k = 4 * lh + 128 * (j >> 2) + (j & 3);
            const int pos = atomicAdd(&cnt[qrow], 1);
            list[qrow * 1024 + pos] = (unsigned int)k | ((unsigned int)bf16_of(p) << 16);
        }
    }
    __syncthreads();

    // ---- sparse PV: lane = (row, e-quad); out_row += p * V[k][:] ----
    const int row = tid >> 5;
    const int eq = tid & 31;
    const int n = cnt[row];
    const ushort_t* Vrow = Vb + base;
    const unsigned int* lrow = list + row * 1024;
    float a0 = 0.f, a1 = 0.f, a2 = 0.f, a3 = 0.f;
    for (int j = 0; j < n; ++j) {
        const unsigned int ent = lrow[j];
        const int k = (int)(ent & 0xFFFFu);
        const float p = f_of_bf16(ent >> 16);
        us4 vv = *reinterpret_cast<const us4*>(Vrow + (size_t)k * 128 + eq * 4);
        a0 += p * f_of_bf16(vv.x);
        a1 += p * f_of_bf16(vv.y);
        a2 += p * f_of_bf16(vv.z);
        a3 += p * f_of_bf16(vv.w);
    }
    const float gsel = sel[b * 8 + h];
    float* orow = out + ((size_t)(b * 1024 + t0 + row)) * 128 + eq * 4;
    atomicAdd(&orow[0], gsel * a0);
    atomicAdd(&orow[1], gsel * a1);
    atomicAdd(&orow[2], gsel * a2);
    atomicAdd(&orow[3], gsel * a3);
}

extern "C" void kernel_launch(void* const* d_in, const int* in_sizes, int n_in,
                              void* d_out, int out_size, void* d_ws, size_t ws_size,
                              hipStream_t stream) {
    (void)in_sizes; (void)n_in; (void)ws_size;
    const float* x   = (const float*)d_in[0];
    const int* mask  = (const int*)d_in[1];
    const float* wq  = (const float*)d_in[2];
    const float* wk  = (const float*)d_in[3];
    const float* wv  = (const float*)d_in[4];
    const float* wsl = (const float*)d_in[5];
    const float* bsl = (const float*)d_in[6];
    float* out = (float*)d_out;

    // ws: sel 4KB | mp 1MB | xb 2MB | Wt 768KB | Q 16MB | K 16MB | V 16MB
    char* wsc = (char*)d_ws;
    float*    sel = (float*)wsc;
    u64*      mp  = (u64*)(wsc + 4096);
    ushort_t* xb  = (ushort_t*)(wsc + 4096 + 1048576);
    ushort_t* Wt  = (ushort_t*)(wsc + 4096 + 1048576 + 2097152);
    ushort_t* Qb  = (ushort_t*)(wsc + 4096 + 1048576 + 2097152 + 786432);
    ushort_t* Kb  = Qb + (size_t)8388608;
    ushort_t* Vb  = Kb + (size_t)8388608;

    hipMemsetAsync(d_out, 0, (size_t)out_size * sizeof(float), stream);
    prep_all<<<3120, 256, 0, stream>>>(x, xb, wq, wk, wv, Wt, mask, mp);
    sel_kernel<<<8, 1024, 0, stream>>>(x, wsl, bsl, sel);
    proj_gemm<<<dim3(128, 48), 256, 0, stream>>>(xb, Wt, Qb, Kb, Vb);
    attn_kernel<<<4096, 512, 0, stream>>>(Qb, Kb, Vb, mp, sel, out);
}